// Round 1
// baseline (552.430 us; speedup 1.0000x reference)
//
#include <hip/hip_runtime.h>
#include <math.h>

#define N_NODES 50000
#define N_EDGES 800000
#define VOCAB 100
#define DIM 128
#define N_GRAPHS 512
#define LN_EPS 1e-5f

// ---------------- degree / counts / dinv ----------------
__global__ void k_deg(const int* __restrict__ dst, int* __restrict__ deg) {
    int e = blockIdx.x * blockDim.x + threadIdx.x;
    if (e < N_EDGES) atomicAdd(&deg[dst[e]], 1);
}

__global__ void k_cnt(const int* __restrict__ batch, int* __restrict__ cnt) {
    int i = blockIdx.x * blockDim.x + threadIdx.x;
    if (i < N_NODES) atomicAdd(&cnt[batch[i]], 1);
}

__global__ void k_dinv(const int* __restrict__ deg, float* __restrict__ dinv) {
    int i = blockIdx.x * blockDim.x + threadIdx.x;
    if (i < N_NODES) dinv[i] = rsqrtf((float)deg[i] + 1.0f);
}

// ---------------- single-block exclusive scan over deg -> rowstart ----------------
__global__ __launch_bounds__(1024) void k_scan(const int* __restrict__ deg,
                                               int* __restrict__ rowstart) {
    __shared__ int sums[1024];
    int tid = threadIdx.x;
    const int chunk = (N_NODES + 1023) / 1024;
    int begin = tid * chunk;
    int end = begin + chunk;
    if (end > N_NODES) end = N_NODES;
    int s = 0;
    for (int i = begin; i < end; i++) s += deg[i];
    sums[tid] = s;
    __syncthreads();
    for (int off = 1; off < 1024; off <<= 1) {
        int v = (tid >= off) ? sums[tid - off] : 0;
        __syncthreads();
        sums[tid] += v;
        __syncthreads();
    }
    int run = (tid > 0) ? sums[tid - 1] : 0;
    for (int i = begin; i < end; i++) { rowstart[i] = run; run += deg[i]; }
    if (begin < N_NODES && end == N_NODES) rowstart[N_NODES] = run;
}

// ---------------- CSR scatter (also packs x[src], dinv[src] per edge) ----------------
__global__ void k_scatter(const int* __restrict__ src, const int* __restrict__ dst,
                          const int* __restrict__ x, const float* __restrict__ dinv,
                          const int* __restrict__ rowstart, int* __restrict__ cursor,
                          int* __restrict__ csr_src, int2* __restrict__ csr_xw) {
    int e = blockIdx.x * blockDim.x + threadIdx.x;
    if (e >= N_EDGES) return;
    int d = dst[e];
    int pos = rowstart[d] + atomicAdd(&cursor[d], 1);
    int s = src[e];
    csr_src[pos] = s;
    csr_xw[pos] = make_int2(x[s], __float_as_int(dinv[s]));
}

// ---------------- EW1 = emb @ W1 (tiny: 100x128) ----------------
__global__ void k_ew1(const float* __restrict__ emb, const float* __restrict__ W1,
                      float* __restrict__ EW1) {
    int idx = blockIdx.x * blockDim.x + threadIdx.x;
    if (idx >= VOCAB * DIM) return;
    int r = idx >> 7, c = idx & 127;
    float acc = 0.f;
    for (int k = 0; k < DIM; k++) acc += emb[r * DIM + k] * W1[k * DIM + c];
    EW1[idx] = acc;
}

// ---------------- layer-1 aggregation + LN + ReLU (EW1 in LDS) ----------------
__global__ __launch_bounds__(256) void k_agg1(
    const float* __restrict__ EW1, const int* __restrict__ x,
    const float* __restrict__ dinv, const int* __restrict__ rowstart,
    const int2* __restrict__ csr_xw,
    const float* __restrict__ b1, const float* __restrict__ g1,
    const float* __restrict__ be1, float2* __restrict__ h1) {
    __shared__ float2 ew[VOCAB * 64];  // 51200 B
    for (int idx = threadIdx.x; idx < VOCAB * 64; idx += blockDim.x)
        ew[idx] = ((const float2*)EW1)[idx];
    __syncthreads();
    int lane = threadIdx.x & 63;
    int wave = (blockIdx.x * blockDim.x + threadIdx.x) >> 6;
    int nw = (gridDim.x * blockDim.x) >> 6;
    float2 bb = make_float2(b1[2 * lane], b1[2 * lane + 1]);
    float2 gg = make_float2(g1[2 * lane], g1[2 * lane + 1]);
    float2 eb = make_float2(be1[2 * lane], be1[2 * lane + 1]);
    for (int i = wave; i < N_NODES; i += nw) {
        float di = dinv[i];
        int xi = x[i];
        float2 e0 = ew[xi * 64 + lane];
        float ax = di * e0.x, ay = di * e0.y;  // self-loop: dinv_i * EW1[x_i]
        int p = rowstart[i], pe = rowstart[i + 1];
        for (; p < pe; p++) {
            int2 xw = csr_xw[p];
            float ds = __int_as_float(xw.y);
            float2 es = ew[xw.x * 64 + lane];
            ax += ds * es.x; ay += ds * es.y;
        }
        float a0 = di * ax + bb.x, a1 = di * ay + bb.y;
        float s = a0 + a1;
        #pragma unroll
        for (int m = 1; m < 64; m <<= 1) s += __shfl_xor(s, m, 64);
        float mu = s * (1.f / 128.f);
        float d0 = a0 - mu, d1 = a1 - mu;
        float q = d0 * d0 + d1 * d1;
        #pragma unroll
        for (int m = 1; m < 64; m <<= 1) q += __shfl_xor(q, m, 64);
        float r = rsqrtf(q * (1.f / 128.f) + LN_EPS);
        float o0 = fmaxf(d0 * r * gg.x + eb.x, 0.f);
        float o1 = fmaxf(d1 * r * gg.y + eb.y, 0.f);
        h1[i * 64 + lane] = make_float2(o0, o1);
    }
}

// ---------------- v2 = dinv * (h1 @ W2), W2 in LDS ----------------
__global__ __launch_bounds__(256) void k_mm2(
    const float* __restrict__ h1, const float* __restrict__ W2,
    const float* __restrict__ dinv, float* __restrict__ v2) {
    __shared__ float w[DIM * DIM];   // 64 KB
    __shared__ float ht[32 * DIM];   // 16 KB
    int t = threadIdx.x;
    for (int idx = t * 4; idx < DIM * DIM; idx += 256 * 4)
        *(float4*)&w[idx] = *(const float4*)&W2[idx];
    int row0 = blockIdx.x * 32;
    for (int idx = t * 4; idx < 32 * DIM; idx += 256 * 4) {
        int r = row0 + (idx >> 7);
        float4 val = make_float4(0.f, 0.f, 0.f, 0.f);
        if (r < N_NODES) val = *(const float4*)&h1[r * DIM + (idx & 127)];
        *(float4*)&ht[idx] = val;
    }
    __syncthreads();
    int ty = t >> 3, tx = t & 7;  // 32 rows x 8 col-groups of 16
    float4 acc[4];
    #pragma unroll
    for (int j = 0; j < 4; j++) acc[j] = make_float4(0.f, 0.f, 0.f, 0.f);
    for (int k = 0; k < DIM; k += 4) {
        float4 a = *(float4*)&ht[ty * DIM + k];
        #pragma unroll
        for (int kk = 0; kk < 4; kk++) {
            float av = (&a.x)[kk];
            #pragma unroll
            for (int j = 0; j < 4; j++) {
                float4 wv = *(float4*)&w[(k + kk) * DIM + tx * 16 + j * 4];
                acc[j].x += av * wv.x; acc[j].y += av * wv.y;
                acc[j].z += av * wv.z; acc[j].w += av * wv.w;
            }
        }
    }
    int row = row0 + ty;
    if (row < N_NODES) {
        float di = dinv[row];
        #pragma unroll
        for (int j = 0; j < 4; j++) {
            float4 o = acc[j];
            o.x *= di; o.y *= di; o.z *= di; o.w *= di;
            *(float4*)&v2[row * DIM + tx * 16 + j * 4] = o;
        }
    }
}

// ---------------- layer-2 aggregation + LN + ReLU + fused mean-pool sums ----------------
__global__ __launch_bounds__(256) void k_agg2(
    const float2* __restrict__ v2, const float* __restrict__ dinv,
    const int* __restrict__ rowstart, const int* __restrict__ csr_src,
    const int* __restrict__ batch,
    const float* __restrict__ b2, const float* __restrict__ g2,
    const float* __restrict__ be2, float* __restrict__ pooled) {
    int lane = threadIdx.x & 63;
    int wave = (blockIdx.x * blockDim.x + threadIdx.x) >> 6;
    int nw = (gridDim.x * blockDim.x) >> 6;
    float2 bb = make_float2(b2[2 * lane], b2[2 * lane + 1]);
    float2 gg = make_float2(g2[2 * lane], g2[2 * lane + 1]);
    float2 eb = make_float2(be2[2 * lane], be2[2 * lane + 1]);
    for (int i = wave; i < N_NODES; i += nw) {
        float di = dinv[i];
        float2 a = v2[i * 64 + lane];   // self-loop: dinv_i*hw_i already folded
        float ax = a.x, ay = a.y;
        int p = rowstart[i], pe = rowstart[i + 1];
        for (; p < pe; p++) {
            int s = csr_src[p];
            float2 vs = v2[s * 64 + lane];
            ax += vs.x; ay += vs.y;
        }
        float a0 = di * ax + bb.x, a1 = di * ay + bb.y;
        float s = a0 + a1;
        #pragma unroll
        for (int m = 1; m < 64; m <<= 1) s += __shfl_xor(s, m, 64);
        float mu = s * (1.f / 128.f);
        float d0 = a0 - mu, d1 = a1 - mu;
        float q = d0 * d0 + d1 * d1;
        #pragma unroll
        for (int m = 1; m < 64; m <<= 1) q += __shfl_xor(q, m, 64);
        float r = rsqrtf(q * (1.f / 128.f) + LN_EPS);
        float o0 = fmaxf(d0 * r * gg.x + eb.x, 0.f);
        float o1 = fmaxf(d1 * r * gg.y + eb.y, 0.f);
        int g = batch[i];
        atomicAdd(&pooled[g * DIM + 2 * lane], o0);
        atomicAdd(&pooled[g * DIM + 2 * lane + 1], o1);
    }
}

// ---------------- out[g] = pooled[g].fcW / max(cnt,1) + fcb ----------------
__global__ void k_out(const float* __restrict__ pooled, const int* __restrict__ cnt,
                      const float* __restrict__ fcW, const float* __restrict__ fcb,
                      float* __restrict__ out) {
    int lane = threadIdx.x & 63;
    int g = (blockIdx.x * blockDim.x + threadIdx.x) >> 6;
    if (g >= N_GRAPHS) return;
    float2 p = ((const float2*)pooled)[g * 64 + lane];
    float2 w = ((const float2*)fcW)[lane];
    float s = p.x * w.x + p.y * w.y;
    #pragma unroll
    for (int m = 1; m < 64; m <<= 1) s += __shfl_xor(s, m, 64);
    if (lane == 0) {
        float c = (float)cnt[g];
        if (c < 1.f) c = 1.f;
        out[g] = s / c + fcb[0];
    }
}

extern "C" void kernel_launch(void* const* d_in, const int* in_sizes, int n_in,
                              void* d_out, int out_size, void* d_ws, size_t ws_size,
                              hipStream_t stream) {
    (void)in_sizes; (void)n_in; (void)out_size; (void)ws_size;
    const int* x    = (const int*)d_in[0];
    const int* src  = (const int*)d_in[1];
    const int* dst  = src + N_EDGES;
    const int* batch = (const int*)d_in[2];
    const float* emb = (const float*)d_in[3];
    const float* W1  = (const float*)d_in[4];
    const float* b1  = (const float*)d_in[5];
    const float* g1  = (const float*)d_in[6];
    const float* be1 = (const float*)d_in[7];
    const float* W2  = (const float*)d_in[8];
    const float* b2  = (const float*)d_in[9];
    const float* g2  = (const float*)d_in[10];
    const float* be2 = (const float*)d_in[11];
    const float* fcW = (const float*)d_in[12];
    const float* fcb = (const float*)d_in[13];
    float* out = (float*)d_out;

    char* wsp = (char*)d_ws;
    size_t off = 0;
    auto alloc = [&](size_t bytes) -> void* {
        void* p = wsp + off;
        off += (bytes + 15) & ~(size_t)15;
        return p;
    };
    int*   deg      = (int*)alloc(N_NODES * 4);
    int*   cursor   = (int*)alloc(N_NODES * 4);
    int*   cnt      = (int*)alloc(N_GRAPHS * 4);
    float* pooled   = (float*)alloc(N_GRAPHS * DIM * 4);
    size_t zero_bytes = off;  // deg, cursor, cnt, pooled must start at 0
    int*   rowstart = (int*)alloc((N_NODES + 1) * 4);
    float* dinv     = (float*)alloc(N_NODES * 4);
    int2*  csr_xw   = (int2*)alloc((size_t)N_EDGES * 8);
    int*   csr_src  = (int*)alloc(N_EDGES * 4);
    float* EW1      = (float*)alloc(VOCAB * DIM * 4);
    float* h1       = (float*)alloc((size_t)N_NODES * DIM * 4);
    float* v2       = (float*)alloc((size_t)N_NODES * DIM * 4);

    hipMemsetAsync(d_ws, 0, zero_bytes, stream);

    k_deg<<<(N_EDGES + 255) / 256, 256, 0, stream>>>(dst, deg);
    k_cnt<<<(N_NODES + 255) / 256, 256, 0, stream>>>(batch, cnt);
    k_dinv<<<(N_NODES + 255) / 256, 256, 0, stream>>>(deg, dinv);
    k_scan<<<1, 1024, 0, stream>>>(deg, rowstart);
    k_scatter<<<(N_EDGES + 255) / 256, 256, 0, stream>>>(src, dst, x, dinv, rowstart,
                                                         cursor, csr_src, csr_xw);
    k_ew1<<<(VOCAB * DIM + 255) / 256, 256, 0, stream>>>(emb, W1, EW1);
    k_agg1<<<1024, 256, 0, stream>>>(EW1, x, dinv, rowstart, csr_xw, b1, g1, be1,
                                     (float2*)h1);
    k_mm2<<<(N_NODES + 31) / 32, 256, 0, stream>>>(h1, W2, dinv, v2);
    k_agg2<<<2048, 256, 0, stream>>>((const float2*)v2, dinv, rowstart, csr_src, batch,
                                     b2, g2, be2, pooled);
    k_out<<<(N_GRAPHS * 64 + 255) / 256, 256, 0, stream>>>(pooled, cnt, fcW, fcb, out);
}

// Round 2
// 480.558 us; speedup vs baseline: 1.1496x; 1.1496x over previous
//
#include <hip/hip_runtime.h>
#include <math.h>

#define N_NODES 50000
#define N_EDGES 800000
#define VOCAB 100
#define DIM 128
#define N_GRAPHS 512
#define LN_EPS 1e-5f

// ---------------- degree / counts / dinv ----------------
__global__ void k_deg(const int* __restrict__ dst, int* __restrict__ deg) {
    int e = blockIdx.x * blockDim.x + threadIdx.x;
    if (e < N_EDGES) atomicAdd(&deg[dst[e]], 1);
}

__global__ void k_cnt(const int* __restrict__ batch, int* __restrict__ cnt) {
    int i = blockIdx.x * blockDim.x + threadIdx.x;
    if (i < N_NODES) atomicAdd(&cnt[batch[i]], 1);
}

__global__ void k_dinv(const int* __restrict__ deg, float* __restrict__ dinv) {
    int i = blockIdx.x * blockDim.x + threadIdx.x;
    if (i < N_NODES) dinv[i] = rsqrtf((float)deg[i] + 1.0f);
}

// ---------------- single-block exclusive scan over deg -> rowstart ----------------
__global__ __launch_bounds__(1024) void k_scan(const int* __restrict__ deg,
                                               int* __restrict__ rowstart) {
    __shared__ int sums[1024];
    int tid = threadIdx.x;
    const int chunk = (N_NODES + 1023) / 1024;
    int begin = tid * chunk;
    int end = begin + chunk;
    if (end > N_NODES) end = N_NODES;
    int s = 0;
    for (int i = begin; i < end; i++) s += deg[i];
    sums[tid] = s;
    __syncthreads();
    for (int off = 1; off < 1024; off <<= 1) {
        int v = (tid >= off) ? sums[tid - off] : 0;
        __syncthreads();
        sums[tid] += v;
        __syncthreads();
    }
    int run = (tid > 0) ? sums[tid - 1] : 0;
    for (int i = begin; i < end; i++) { rowstart[i] = run; run += deg[i]; }
    if (begin < N_NODES && end == N_NODES) rowstart[N_NODES] = run;
}

// ---------------- CSR scatter (also packs x[src], dinv[src] per edge) ----------------
__global__ void k_scatter(const int* __restrict__ src, const int* __restrict__ dst,
                          const int* __restrict__ x, const float* __restrict__ dinv,
                          const int* __restrict__ rowstart, int* __restrict__ cursor,
                          int* __restrict__ csr_src, int2* __restrict__ csr_xw) {
    int e = blockIdx.x * blockDim.x + threadIdx.x;
    if (e >= N_EDGES) return;
    int d = dst[e];
    int pos = rowstart[d] + atomicAdd(&cursor[d], 1);
    int s = src[e];
    csr_src[pos] = s;
    csr_xw[pos] = make_int2(x[s], __float_as_int(dinv[s]));
}

// ---------------- EW1 = emb @ W1 (tiny: 100x128) ----------------
__global__ void k_ew1(const float* __restrict__ emb, const float* __restrict__ W1,
                      float* __restrict__ EW1) {
    int idx = blockIdx.x * blockDim.x + threadIdx.x;
    if (idx >= VOCAB * DIM) return;
    int r = idx >> 7, c = idx & 127;
    float acc = 0.f;
    for (int k = 0; k < DIM; k++) acc += emb[r * DIM + k] * W1[k * DIM + c];
    EW1[idx] = acc;
}

// ---------------- layer-1 aggregation + LN + ReLU (EW1 in LDS) ----------------
// Chunked edge processing: each lane loads one edge (coalesced), then a
// broadcast j-loop accumulates. No dependent global load in the inner loop.
__global__ __launch_bounds__(256) void k_agg1(
    const float* __restrict__ EW1, const int* __restrict__ x,
    const float* __restrict__ dinv, const int* __restrict__ rowstart,
    const int2* __restrict__ csr_xw,
    const float* __restrict__ b1, const float* __restrict__ g1,
    const float* __restrict__ be1, float2* __restrict__ h1) {
    __shared__ float2 ew[VOCAB * 64];  // 51200 B
    for (int idx = threadIdx.x; idx < VOCAB * 64; idx += blockDim.x)
        ew[idx] = ((const float2*)EW1)[idx];
    __syncthreads();
    int lane = threadIdx.x & 63;
    int wave = (blockIdx.x * blockDim.x + threadIdx.x) >> 6;
    int nw = (gridDim.x * blockDim.x) >> 6;
    float2 bb = make_float2(b1[2 * lane], b1[2 * lane + 1]);
    float2 gg = make_float2(g1[2 * lane], g1[2 * lane + 1]);
    float2 eb = make_float2(be1[2 * lane], be1[2 * lane + 1]);
    for (int i = wave; i < N_NODES; i += nw) {
        float di = dinv[i];
        int xi = x[i];
        float2 e0 = ew[xi * 64 + lane];
        float ax = di * e0.x, ay = di * e0.y;  // self-loop: dinv_i * EW1[x_i]
        int p = rowstart[i], pe = rowstart[i + 1];
        while (p < pe) {
            int n = pe - p; if (n > 64) n = 64;
            int2 my = make_int2(0, 0);
            if (lane < n) my = csr_xw[p + lane];
            int j = 0;
            for (; j + 8 <= n; j += 8) {
                #pragma unroll
                for (int u = 0; u < 8; u++) {
                    int xv = __shfl(my.x, j + u, 64);
                    float ds = __int_as_float(__shfl(my.y, j + u, 64));
                    float2 es = ew[xv * 64 + lane];
                    ax += ds * es.x; ay += ds * es.y;
                }
            }
            for (; j < n; j++) {
                int xv = __shfl(my.x, j, 64);
                float ds = __int_as_float(__shfl(my.y, j, 64));
                float2 es = ew[xv * 64 + lane];
                ax += ds * es.x; ay += ds * es.y;
            }
            p += n;
        }
        float a0 = di * ax + bb.x, a1 = di * ay + bb.y;
        float s = a0 + a1;
        #pragma unroll
        for (int m = 1; m < 64; m <<= 1) s += __shfl_xor(s, m, 64);
        float mu = s * (1.f / 128.f);
        float d0 = a0 - mu, d1 = a1 - mu;
        float q = d0 * d0 + d1 * d1;
        #pragma unroll
        for (int m = 1; m < 64; m <<= 1) q += __shfl_xor(q, m, 64);
        float r = rsqrtf(q * (1.f / 128.f) + LN_EPS);
        float o0 = fmaxf(d0 * r * gg.x + eb.x, 0.f);
        float o1 = fmaxf(d1 * r * gg.y + eb.y, 0.f);
        h1[i * 64 + lane] = make_float2(o0, o1);
    }
}

// ---------------- v2 = dinv * (h1 @ W2), W2 in LDS ----------------
__global__ __launch_bounds__(256) void k_mm2(
    const float* __restrict__ h1, const float* __restrict__ W2,
    const float* __restrict__ dinv, float* __restrict__ v2) {
    __shared__ float w[DIM * DIM];   // 64 KB
    __shared__ float ht[32 * DIM];   // 16 KB
    int t = threadIdx.x;
    for (int idx = t * 4; idx < DIM * DIM; idx += 256 * 4)
        *(float4*)&w[idx] = *(const float4*)&W2[idx];
    int row0 = blockIdx.x * 32;
    for (int idx = t * 4; idx < 32 * DIM; idx += 256 * 4) {
        int r = row0 + (idx >> 7);
        float4 val = make_float4(0.f, 0.f, 0.f, 0.f);
        if (r < N_NODES) val = *(const float4*)&h1[r * DIM + (idx & 127)];
        *(float4*)&ht[idx] = val;
    }
    __syncthreads();
    int ty = t >> 3, tx = t & 7;  // 32 rows x 8 col-groups of 16
    float4 acc[4];
    #pragma unroll
    for (int j = 0; j < 4; j++) acc[j] = make_float4(0.f, 0.f, 0.f, 0.f);
    for (int k = 0; k < DIM; k += 4) {
        float4 a = *(float4*)&ht[ty * DIM + k];
        #pragma unroll
        for (int kk = 0; kk < 4; kk++) {
            float av = (&a.x)[kk];
            #pragma unroll
            for (int j = 0; j < 4; j++) {
                float4 wv = *(float4*)&w[(k + kk) * DIM + tx * 16 + j * 4];
                acc[j].x += av * wv.x; acc[j].y += av * wv.y;
                acc[j].z += av * wv.z; acc[j].w += av * wv.w;
            }
        }
    }
    int row = row0 + ty;
    if (row < N_NODES) {
        float di = dinv[row];
        #pragma unroll
        for (int j = 0; j < 4; j++) {
            float4 o = acc[j];
            o.x *= di; o.y *= di; o.z *= di; o.w *= di;
            *(float4*)&v2[row * DIM + tx * 16 + j * 4] = o;
        }
    }
}

// ---------------- layer-2 aggregation + LN + ReLU + fused mean-pool sums ----------------
// Same chunked pattern; v2 row gathers are issued 8-deep (independent) instead
// of serialized behind a scalar csr_src load.
__global__ __launch_bounds__(256) void k_agg2(
    const float2* __restrict__ v2, const float* __restrict__ dinv,
    const int* __restrict__ rowstart, const int* __restrict__ csr_src,
    const int* __restrict__ batch,
    const float* __restrict__ b2, const float* __restrict__ g2,
    const float* __restrict__ be2, float* __restrict__ pooled) {
    int lane = threadIdx.x & 63;
    int wave = (blockIdx.x * blockDim.x + threadIdx.x) >> 6;
    int nw = (gridDim.x * blockDim.x) >> 6;
    float2 bb = make_float2(b2[2 * lane], b2[2 * lane + 1]);
    float2 gg = make_float2(g2[2 * lane], g2[2 * lane + 1]);
    float2 eb = make_float2(be2[2 * lane], be2[2 * lane + 1]);
    for (int i = wave; i < N_NODES; i += nw) {
        float di = dinv[i];
        float2 a = v2[i * 64 + lane];   // self-loop: dinv_i*hw_i already folded
        float ax = a.x, ay = a.y;
        int p = rowstart[i], pe = rowstart[i + 1];
        while (p < pe) {
            int n = pe - p; if (n > 64) n = 64;
            int mys = 0;
            if (lane < n) mys = csr_src[p + lane];
            int j = 0;
            for (; j + 8 <= n; j += 8) {
                #pragma unroll
                for (int u = 0; u < 8; u++) {
                    int s = __shfl(mys, j + u, 64);
                    float2 vs = v2[s * 64 + lane];
                    ax += vs.x; ay += vs.y;
                }
            }
            for (; j < n; j++) {
                int s = __shfl(mys, j, 64);
                float2 vs = v2[s * 64 + lane];
                ax += vs.x; ay += vs.y;
            }
            p += n;
        }
        float a0 = di * ax + bb.x, a1 = di * ay + bb.y;
        float s = a0 + a1;
        #pragma unroll
        for (int m = 1; m < 64; m <<= 1) s += __shfl_xor(s, m, 64);
        float mu = s * (1.f / 128.f);
        float d0 = a0 - mu, d1 = a1 - mu;
        float q = d0 * d0 + d1 * d1;
        #pragma unroll
        for (int m = 1; m < 64; m <<= 1) q += __shfl_xor(q, m, 64);
        float r = rsqrtf(q * (1.f / 128.f) + LN_EPS);
        float o0 = fmaxf(d0 * r * gg.x + eb.x, 0.f);
        float o1 = fmaxf(d1 * r * gg.y + eb.y, 0.f);
        int g = batch[i];
        atomicAdd(&pooled[g * DIM + 2 * lane], o0);
        atomicAdd(&pooled[g * DIM + 2 * lane + 1], o1);
    }
}

// ---------------- out[g] = pooled[g].fcW / max(cnt,1) + fcb ----------------
__global__ void k_out(const float* __restrict__ pooled, const int* __restrict__ cnt,
                      const float* __restrict__ fcW, const float* __restrict__ fcb,
                      float* __restrict__ out) {
    int lane = threadIdx.x & 63;
    int g = (blockIdx.x * blockDim.x + threadIdx.x) >> 6;
    if (g >= N_GRAPHS) return;
    float2 p = ((const float2*)pooled)[g * 64 + lane];
    float2 w = ((const float2*)fcW)[lane];
    float s = p.x * w.x + p.y * w.y;
    #pragma unroll
    for (int m = 1; m < 64; m <<= 1) s += __shfl_xor(s, m, 64);
    if (lane == 0) {
        float c = (float)cnt[g];
        if (c < 1.f) c = 1.f;
        out[g] = s / c + fcb[0];
    }
}

extern "C" void kernel_launch(void* const* d_in, const int* in_sizes, int n_in,
                              void* d_out, int out_size, void* d_ws, size_t ws_size,
                              hipStream_t stream) {
    (void)in_sizes; (void)n_in; (void)out_size; (void)ws_size;
    const int* x    = (const int*)d_in[0];
    const int* src  = (const int*)d_in[1];
    const int* dst  = src + N_EDGES;
    const int* batch = (const int*)d_in[2];
    const float* emb = (const float*)d_in[3];
    const float* W1  = (const float*)d_in[4];
    const float* b1  = (const float*)d_in[5];
    const float* g1  = (const float*)d_in[6];
    const float* be1 = (const float*)d_in[7];
    const float* W2  = (const float*)d_in[8];
    const float* b2  = (const float*)d_in[9];
    const float* g2  = (const float*)d_in[10];
    const float* be2 = (const float*)d_in[11];
    const float* fcW = (const float*)d_in[12];
    const float* fcb = (const float*)d_in[13];
    float* out = (float*)d_out;

    char* wsp = (char*)d_ws;
    size_t off = 0;
    auto alloc = [&](size_t bytes) -> void* {
        void* p = wsp + off;
        off += (bytes + 15) & ~(size_t)15;
        return p;
    };
    int*   deg      = (int*)alloc(N_NODES * 4);
    int*   cursor   = (int*)alloc(N_NODES * 4);
    int*   cnt      = (int*)alloc(N_GRAPHS * 4);
    float* pooled   = (float*)alloc(N_GRAPHS * DIM * 4);
    size_t zero_bytes = off;  // deg, cursor, cnt, pooled must start at 0
    int*   rowstart = (int*)alloc((N_NODES + 1) * 4);
    float* dinv     = (float*)alloc(N_NODES * 4);
    int2*  csr_xw   = (int2*)alloc((size_t)N_EDGES * 8);
    int*   csr_src  = (int*)alloc(N_EDGES * 4);
    float* EW1      = (float*)alloc(VOCAB * DIM * 4);
    float* h1       = (float*)alloc((size_t)N_NODES * DIM * 4);
    float* v2       = (float*)alloc((size_t)N_NODES * DIM * 4);

    hipMemsetAsync(d_ws, 0, zero_bytes, stream);

    k_deg<<<(N_EDGES + 255) / 256, 256, 0, stream>>>(dst, deg);
    k_cnt<<<(N_NODES + 255) / 256, 256, 0, stream>>>(batch, cnt);
    k_dinv<<<(N_NODES + 255) / 256, 256, 0, stream>>>(deg, dinv);
    k_scan<<<1, 1024, 0, stream>>>(deg, rowstart);
    k_scatter<<<(N_EDGES + 255) / 256, 256, 0, stream>>>(src, dst, x, dinv, rowstart,
                                                         cursor, csr_src, csr_xw);
    k_ew1<<<(VOCAB * DIM + 255) / 256, 256, 0, stream>>>(emb, W1, EW1);
    // 768 blocks = 3 blocks/CU (LDS-capped) with no scheduling tail
    k_agg1<<<768, 256, 0, stream>>>(EW1, x, dinv, rowstart, csr_xw, b1, g1, be1,
                                    (float2*)h1);
    k_mm2<<<(N_NODES + 31) / 32, 256, 0, stream>>>(h1, W2, dinv, v2);
    k_agg2<<<2048, 256, 0, stream>>>((const float2*)v2, dinv, rowstart, csr_src, batch,
                                     b2, g2, be2, pooled);
    k_out<<<(N_GRAPHS * 64 + 255) / 256, 256, 0, stream>>>(pooled, cnt, fcW, fcb, out);
}